// Round 7
// baseline (403.210 us; speedup 1.0000x reference)
//
#include <hip/hip_runtime.h>
#include <math.h>

// Problem constants (fixed by the reference).
#define Bsz 64
#define Ssz 14
#define Isz 32
#define Csz 10
#define Dsz 16
#define Nsz (Ssz*Ssz*Isz)   // 6272
#define EPSF 1e-9f

#define CH   448            // n's per chunk; 14*448 == 6272 EXACTLY -> no bounds checks
#define NCH  14
#define BLK  640            // 10 waves, wave = class
#define ITER (CH/64)        // 7 loop iterations per phase per wave

// vote = pose(4x4) @ Wr(4x4, REGISTERS) + coords on elems 0,1. Pure VALU.
__device__ __forceinline__ void vote_reg(const float* p, const float* Wr,
                                         float chh, float cww, float* v)
{
#pragma unroll
    for (int pr = 0; pr < 4; ++pr)
#pragma unroll
        for (int r = 0; r < 4; ++r)
            v[pr*4+r] = p[pr*4+0]*Wr[0*4+r] + p[pr*4+1]*Wr[1*4+r]
                      + p[pr*4+2]*Wr[2*4+r] + p[pr*4+3]*Wr[3*4+r];
    v[0] += chh;
    v[1] += cww;
}

// Each lane's loop-invariant W matrix: i = lane&31, class c. 16 VGPRs.
__device__ __forceinline__ void load_W_regs(const float* __restrict__ w,
                                            int lane, int c, float* Wr)
{
    const float4* ws = reinterpret_cast<const float4*>(w + (((lane & 31)*Csz + c) * Dsz));
    float4 b0 = ws[0], b1 = ws[1], b2 = ws[2], b3 = ws[3];
    Wr[0]=b0.x; Wr[1]=b0.y; Wr[2]=b0.z; Wr[3]=b0.w;
    Wr[4]=b1.x; Wr[5]=b1.y; Wr[6]=b1.z; Wr[7]=b1.w;
    Wr[8]=b2.x; Wr[9]=b2.y; Wr[10]=b2.z; Wr[11]=b2.w;
    Wr[12]=b3.x; Wr[13]=b3.y; Wr[14]=b3.z; Wr[15]=b3.w;
}

// Stage pose chunk into plane-major LDS: Pl[r][n][4], r = quarter-row.
// Read addr (r*CH+nl)*16B -> bank 4*nl%32: 8-lane period covers all 32 banks
// -> CONFLICT-FREE b128 reads (round-6 layout was 32-way conflicted).
__device__ __forceinline__ void stage_pose(const float* __restrict__ poseb,
                                           int base, int tid, float* Pl)
{
    const float4* gp = reinterpret_cast<const float4*>(poseb + (size_t)base * Dsz);
    float4* lp = reinterpret_cast<float4*>(Pl);
    for (int f = tid; f < CH*4; f += BLK)
        lp[(f & 3)*CH + (f >> 2)] = gp[f];
}

__device__ __forceinline__ void load_pose_lds(const float* Pl, int nl, float* p)
{
    const float4* q = reinterpret_cast<const float4*>(Pl);
    float4 a0 = q[0*CH + nl], a1 = q[1*CH + nl], a2 = q[2*CH + nl], a3 = q[3*CH + nl];
    p[0]=a0.x; p[1]=a0.y; p[2]=a0.z; p[3]=a0.w;
    p[4]=a1.x; p[5]=a1.y; p[6]=a1.z; p[7]=a1.w;
    p[8]=a2.x; p[9]=a2.y; p[10]=a2.z; p[11]=a2.w;
    p[12]=a3.x; p[13]=a3.y; p[14]=a3.z; p[15]=a3.w;
}

// ---------------------------------------------------------------------------
// M0: uniform-rr M-step partials. Block=(b,chunk), wave=class.
// Also zeroes the em2 last-block tickets (stream-ordered before em2).
// ---------------------------------------------------------------------------
__global__ __launch_bounds__(BLK) void m0_kernel(
    const float* __restrict__ pose,     // [B][N][16]
    const float* __restrict__ act,      // [B][N]
    const float* __restrict__ w,        // [I][C][16]
    float* __restrict__ partials,       // [B*C][NCH][33]
    int* __restrict__ tickets)          // [B]
{
    const int b = blockIdx.x, chunk = blockIdx.y;
    const int tid = threadIdx.x, c = tid >> 6, lane = tid & 63;
    const int base = chunk * CH;

    if (b == 0 && chunk == 0 && tid < Bsz) tickets[tid] = 0;

    __shared__ float Pl[4*CH*4];        // 28672 B, plane-major

    const float* poseb = pose + (size_t)b * Nsz * Dsz;
    stage_pose(poseb, base, tid, Pl);

    float Wr[16];
    load_W_regs(w, lane, c, Wr);
    __syncthreads();

    float s0 = 0.f, s1[Dsz], s2[Dsz];
#pragma unroll
    for (int d = 0; d < Dsz; ++d) { s1[d] = 0.f; s2[d] = 0.f; }

    const float* actb = act + (size_t)b * Nsz;

    for (int it = 0; it < ITER; ++it) {
        const int nl = it*64 + lane;
        const int n  = base + nl;
        float p[16];
        load_pose_lds(Pl, nl, p);
        int hw = n >> 5;
        int wc = hw % Ssz, hr = hw / Ssz;
        float wgt = actb[n] * (1.0f/Csz);
        float v[16];
        vote_reg(p, Wr, (hr+0.5f)*(1.0f/Ssz), (wc+0.5f)*(1.0f/Ssz), v);
        s0 += wgt;
#pragma unroll
        for (int d = 0; d < Dsz; ++d) {
            float wv = wgt * v[d];
            s1[d] += wv;
            s2[d] += wv * v[d];
        }
    }

#pragma unroll
    for (int m = 32; m >= 1; m >>= 1) {
        s0 += __shfl_xor(s0, m);
#pragma unroll
        for (int d = 0; d < Dsz; ++d) {
            s1[d] += __shfl_xor(s1[d], m);
            s2[d] += __shfl_xor(s2[d], m);
        }
    }
    if (lane == 0) {
        float* pt = partials + ((size_t)(b*Csz + c)*NCH + chunk)*33;
        pt[0] = s0;
#pragma unroll
        for (int d = 0; d < Dsz; ++d) { pt[1+d] = s1[d]; pt[17+d] = s2[d]; }
    }
}

// ---------------------------------------------------------------------------
// Fused finalize(prev) + E + M (+ optional last-block output finalize).
// Block=(b,chunk), 10 waves = 10 classes, conflict-free Pl, quad 4-way tree.
// ---------------------------------------------------------------------------
__global__ __launch_bounds__(BLK) void em_kernel(
    const float* __restrict__ pose,     // [B][N][16]
    const float* __restrict__ act,      // [B][N]
    const float* __restrict__ w,        // [I][C][16]
    const float* __restrict__ beta_v,   // [C]
    const float* __restrict__ beta_a,   // [C]
    const float* __restrict__ part_in,  // [B*C][NCH][33]
    float* __restrict__ part_out,       // [B*C][NCH][33]
    float inv_temp_prev,
    int final_it, float inv_temp_final,
    int* __restrict__ tickets,          // [B]
    float* __restrict__ out)            // [B][C][16] then [B][C]
{
    const int b = blockIdx.x, chunk = blockIdx.y;
    const int tid = threadIdx.x, wv = tid >> 6, lane = tid & 63;
    const int base = chunk * CH;

    __shared__ float Pl[4*CH*4];        // 28672 B
    __shared__ float zz[CH][11];        // 19712 B (stride 11 coprime 32)
    __shared__ float Sv[Csz][33];
    __shared__ float prm[Csz][33];      // mean16, invd16, K
    __shared__ float lg[Csz][16];
    __shared__ int isLast;

    const float* poseb = pose + (size_t)b * Nsz * Dsz;
    stage_pose(poseb, base, tid, Pl);

    float Wr[16];
    load_W_regs(w, lane, wv, Wr);

    // ---- phase F: reduce prev partials for this b -> prm ----
    if (tid < Csz*33) {
        int c = tid / 33, j = tid - c*33;
        const float* pp = part_in + ((size_t)(b*Csz + c)*NCH)*33 + j;
        float s = 0.f;
        for (int ch2 = 0; ch2 < NCH; ++ch2) s += pp[ch2*33];
        Sv[c][j] = s;
    }
    __syncthreads();
    if (tid < Csz*Dsz) {
        int c = tid >> 4, d = tid & 15;
        float S0 = Sv[c][0];
        float mn  = Sv[c][1+d] / S0;
        float var = fmaxf(Sv[c][17+d] / S0 - mn*mn, 0.f);
        prm[c][d]    = mn;
        prm[c][16+d] = 1.f / (2.f*var + EPSF);
        lg[c][d]     = __logf(sqrtf(var) + EPSF);
    }
    __syncthreads();
    if (tid < Csz) {
        int c = tid;
        float sumlog = 0.f;
#pragma unroll
        for (int d = 0; d < Dsz; ++d) sumlog += lg[c][d];
        float cost = Sv[c][0] * (16.f * beta_v[c] + sumlog);
        float oact = 1.f / (1.f + __expf(-inv_temp_prev * (beta_a[c] - cost)));
        prm[c][32] = __logf(oact + EPSF) - sumlog;    // K[c]
    }
    __syncthreads();

    // ---- E phase: wave wv computes zz[.][wv]; quad as 4-way tree ----
    {
        float mn[Dsz], iv[Dsz];
#pragma unroll
        for (int d = 0; d < Dsz; ++d) { mn[d] = prm[wv][d]; iv[d] = prm[wv][16+d]; }
        float Kc = prm[wv][32];

        for (int it = 0; it < ITER; ++it) {
            const int nl = it*64 + lane;
            const int n  = base + nl;
            float p[16];
            load_pose_lds(Pl, nl, p);
            int hw = n >> 5;
            int wc = hw % Ssz, hr = hw / Ssz;
            float v[16];
            vote_reg(p, Wr, (hr+0.5f)*(1.0f/Ssz), (wc+0.5f)*(1.0f/Ssz), v);
            float qa = 0.f, qb = 0.f, qc = 0.f, qd = 0.f;
#pragma unroll
            for (int d = 0; d < 4; ++d) {
                float d0 = v[d]    - mn[d];    qa += d0*d0*iv[d];
                float d1 = v[4+d]  - mn[4+d];  qb += d1*d1*iv[4+d];
                float d2 = v[8+d]  - mn[8+d];  qc += d2*d2*iv[8+d];
                float d3 = v[12+d] - mn[12+d]; qd += d3*d3*iv[12+d];
            }
            zz[nl][wv] = Kc - ((qa+qb)+(qc+qd));
        }
    }
    __syncthreads();

    // ---- softmax over c: thread-per-n (first CH threads), in place ----
    if (tid < CH) {
        const int n = base + tid;
        float z[Csz];
#pragma unroll
        for (int c = 0; c < Csz; ++c) z[c] = zz[tid][c];
        float zmax = z[0];
#pragma unroll
        for (int c = 1; c < Csz; ++c) zmax = fmaxf(zmax, z[c]);
        float zsum = 0.f;
#pragma unroll
        for (int c = 0; c < Csz; ++c) { z[c] = __expf(z[c] - zmax); zsum += z[c]; }
        float sc = __fdividef(act[(size_t)b*Nsz + n], zsum);
#pragma unroll
        for (int c = 0; c < Csz; ++c) zz[tid][c] = z[c] * sc;
    }
    __syncthreads();

    // ---- M phase: wave wv accumulates (pose + rr from LDS) ----
    float s0 = 0.f, s1[Dsz], s2[Dsz];
#pragma unroll
    for (int d = 0; d < Dsz; ++d) { s1[d] = 0.f; s2[d] = 0.f; }

    for (int it = 0; it < ITER; ++it) {
        const int nl = it*64 + lane;
        const int n  = base + nl;
        float p[16];
        load_pose_lds(Pl, nl, p);
        int hw = n >> 5;
        int wc = hw % Ssz, hr = hw / Ssz;
        float wgt = zz[nl][wv];
        float v[16];
        vote_reg(p, Wr, (hr+0.5f)*(1.0f/Ssz), (wc+0.5f)*(1.0f/Ssz), v);
        s0 += wgt;
#pragma unroll
        for (int d = 0; d < Dsz; ++d) {
            float wvv = wgt * v[d];
            s1[d] += wvv;
            s2[d] += wvv * v[d];
        }
    }

#pragma unroll
    for (int m = 32; m >= 1; m >>= 1) {
        s0 += __shfl_xor(s0, m);
#pragma unroll
        for (int d = 0; d < Dsz; ++d) {
            s1[d] += __shfl_xor(s1[d], m);
            s2[d] += __shfl_xor(s2[d], m);
        }
    }
    if (lane == 0) {
        float* pt = part_out + ((size_t)(b*Csz + wv)*NCH + chunk)*33;
        pt[0] = s0;
#pragma unroll
        for (int d = 0; d < Dsz; ++d) { pt[1+d] = s1[d]; pt[17+d] = s2[d]; }
    }

    // ---- last-block output finalize (em2 only): saves the fin dispatch ----
    if (final_it) {
        __threadfence();
        if (tid == 0) {
            int r = atomicAdd(&tickets[b], 1);
            isLast = (r == NCH - 1);
        }
        __syncthreads();
        if (isLast) {
            __threadfence();    // acquire: see all blocks' partials
            if (tid < Csz*33) {
                int c = tid / 33, j = tid - c*33;
                const float* pp = part_out + ((size_t)(b*Csz + c)*NCH)*33 + j;
                float s = 0.f;
                for (int ch2 = 0; ch2 < NCH; ++ch2) s += pp[ch2*33];
                Sv[c][j] = s;
            }
            __syncthreads();
            if (tid < Csz*Dsz) {
                int c = tid >> 4, d = tid & 15;
                float S0 = Sv[c][0];
                float mn  = Sv[c][1+d] / S0;
                float var = fmaxf(Sv[c][17+d] / S0 - mn*mn, 0.f);
                lg[c][d] = __logf(sqrtf(var) + EPSF);
                out[(size_t)(b*Csz + c)*Dsz + d] = mn;
            }
            __syncthreads();
            if (tid < Csz) {
                int c = tid;
                float sumlog = 0.f;
#pragma unroll
                for (int d = 0; d < Dsz; ++d) sumlog += lg[c][d];
                float cost = Sv[c][0] * (16.f * beta_v[c] + sumlog);
                float oact = 1.f / (1.f + __expf(-inv_temp_final * (beta_a[c] - cost)));
                out[Bsz*Csz*Dsz + b*Csz + c] = oact;
            }
        }
    }
}

// ---------------------------------------------------------------------------
// 3 dispatches: M0 -> EM1 -> EM2(+lastblock fin).
// Workspace: partials A,B = 2 x 640*14*33 floats (2.36 MB) + tickets[64].
// ---------------------------------------------------------------------------
extern "C" void kernel_launch(void* const* d_in, const int* in_sizes, int n_in,
                              void* d_out, int out_size, void* d_ws, size_t ws_size,
                              hipStream_t stream)
{
    const float* pose = (const float*)d_in[0];
    const float* act  = (const float*)d_in[1];
    const float* w    = (const float*)d_in[2];
    const float* bv   = (const float*)d_in[3];
    const float* ba   = (const float*)d_in[4];
    float* out = (float*)d_out;

    float* partA = (float*)d_ws;
    float* partB = partA + (size_t)Bsz*Csz*NCH*33;
    int* tickets = (int*)(partB + (size_t)Bsz*Csz*NCH*33);

    dim3 grid(Bsz, NCH);

    m0_kernel<<<grid, BLK, 0, stream>>>(pose, act, w, partA, tickets);
    em_kernel<<<grid, BLK, 0, stream>>>(pose, act, w, bv, ba, partA, partB,
                                        1.0f, 0, 0.0f, tickets, out);
    em_kernel<<<grid, BLK, 0, stream>>>(pose, act, w, bv, ba, partB, partA,
                                        2.0f, 1, 3.0f, tickets, out);
}

// Round 8
// 237.642 us; speedup vs baseline: 1.6967x; 1.6967x over previous
//
#include <hip/hip_runtime.h>
#include <math.h>

// Problem constants (fixed by the reference).
#define Bsz 64
#define Ssz 14
#define Isz 32
#define Csz 10
#define Dsz 16
#define Nsz (Ssz*Ssz*Isz)   // 6272
#define EPSF 1e-9f

#define CH   448            // n's per chunk; 14*448 == 6272 EXACTLY -> no bounds checks
#define NCH  14
#define BLK  640            // 10 waves, wave = class
#define ITER (CH/64)        // 7 loop iterations per phase per wave
#define NCOPY 8             // butterfly stops at 8-lane groups -> 8 partial copies

// vote = pose(4x4) @ Wr(4x4, REGISTERS) + coords on elems 0,1. Pure VALU.
__device__ __forceinline__ void vote_reg(const float* p, const float* Wr,
                                         float chh, float cww, float* v)
{
#pragma unroll
    for (int pr = 0; pr < 4; ++pr)
#pragma unroll
        for (int r = 0; r < 4; ++r)
            v[pr*4+r] = p[pr*4+0]*Wr[0*4+r] + p[pr*4+1]*Wr[1*4+r]
                      + p[pr*4+2]*Wr[2*4+r] + p[pr*4+3]*Wr[3*4+r];
    v[0] += chh;
    v[1] += cww;
}

// Each lane's loop-invariant W matrix: i = lane&31, class c. 16 VGPRs.
__device__ __forceinline__ void load_W_regs(const float* __restrict__ w,
                                            int lane, int c, float* Wr)
{
    const float4* ws = reinterpret_cast<const float4*>(w + (((lane & 31)*Csz + c) * Dsz));
    float4 b0 = ws[0], b1 = ws[1], b2 = ws[2], b3 = ws[3];
    Wr[0]=b0.x; Wr[1]=b0.y; Wr[2]=b0.z; Wr[3]=b0.w;
    Wr[4]=b1.x; Wr[5]=b1.y; Wr[6]=b1.z; Wr[7]=b1.w;
    Wr[8]=b2.x; Wr[9]=b2.y; Wr[10]=b2.z; Wr[11]=b2.w;
    Wr[12]=b3.x; Wr[13]=b3.y; Wr[14]=b3.z; Wr[15]=b3.w;
}

// Plane-major pose LDS: Pl[r][n][4] (r = quarter-row). Conflict-light b128.
__device__ __forceinline__ void stage_pose(const float* __restrict__ poseb,
                                           int base, int tid, float* Pl)
{
    const float4* gp = reinterpret_cast<const float4*>(poseb + (size_t)base * Dsz);
    float4* lp = reinterpret_cast<float4*>(Pl);
    for (int f = tid; f < CH*4; f += BLK)
        lp[(f & 3)*CH + (f >> 2)] = gp[f];
}

__device__ __forceinline__ void load_pose_lds(const float* Pl, int nl, float* p)
{
    const float4* q = reinterpret_cast<const float4*>(Pl);
    float4 a0 = q[0*CH + nl], a1 = q[1*CH + nl], a2 = q[2*CH + nl], a3 = q[3*CH + nl];
    p[0]=a0.x; p[1]=a0.y; p[2]=a0.z; p[3]=a0.w;
    p[4]=a1.x; p[5]=a1.y; p[6]=a1.z; p[7]=a1.w;
    p[8]=a2.x; p[9]=a2.y; p[10]=a2.z; p[11]=a2.w;
    p[12]=a3.x; p[13]=a3.y; p[14]=a3.z; p[15]=a3.w;
}

// Short butterfly (xor 1,2,4 -> 8-lane group sums), lanes 8k write copy k.
// Saves 99 ds_swizzle + 99 adds per wave vs the full 6-step butterfly.
__device__ __forceinline__ void reduce_store(float s0, float* s1, float* s2,
                                             float* __restrict__ pt, int lane)
{
#pragma unroll
    for (int m = 1; m <= 4; m <<= 1) {
        s0 += __shfl_xor(s0, m);
#pragma unroll
        for (int d = 0; d < Dsz; ++d) {
            s1[d] += __shfl_xor(s1[d], m);
            s2[d] += __shfl_xor(s2[d], m);
        }
    }
    if ((lane & 7) == 0) {
        float* po = pt + (lane >> 3) * 33;
        po[0] = s0;
#pragma unroll
        for (int d = 0; d < Dsz; ++d) { po[1+d] = s1[d]; po[17+d] = s2[d]; }
    }
}

// ---------------------------------------------------------------------------
// M0: uniform-rr M-step partials. Block=(b,chunk), wave=class.
// ---------------------------------------------------------------------------
__global__ __launch_bounds__(BLK) void m0_kernel(
    const float* __restrict__ pose,     // [B][N][16]
    const float* __restrict__ act,      // [B][N]
    const float* __restrict__ w,        // [I][C][16]
    float* __restrict__ partials)       // [B*C][NCH][8][33]
{
    const int b = blockIdx.x, chunk = blockIdx.y;
    const int tid = threadIdx.x, c = tid >> 6, lane = tid & 63;
    const int base = chunk * CH;

    __shared__ float Pl[4*CH*4];        // 28672 B, plane-major

    const float* poseb = pose + (size_t)b * Nsz * Dsz;
    stage_pose(poseb, base, tid, Pl);

    float Wr[16];
    load_W_regs(w, lane, c, Wr);
    __syncthreads();

    float s0 = 0.f, s1[Dsz], s2[Dsz];
#pragma unroll
    for (int d = 0; d < Dsz; ++d) { s1[d] = 0.f; s2[d] = 0.f; }

    const float* actb = act + (size_t)b * Nsz;

    for (int it = 0; it < ITER; ++it) {
        const int nl = it*64 + lane;
        const int n  = base + nl;
        float p[16];
        load_pose_lds(Pl, nl, p);
        int hw = n >> 5;
        int wc = hw % Ssz, hr = hw / Ssz;
        float wgt = actb[n] * (1.0f/Csz);
        float v[16];
        vote_reg(p, Wr, (hr+0.5f)*(1.0f/Ssz), (wc+0.5f)*(1.0f/Ssz), v);
        s0 += wgt;
#pragma unroll
        for (int d = 0; d < Dsz; ++d) {
            float wv = wgt * v[d];
            s1[d] += wv;
            s2[d] += wv * v[d];
        }
    }

    float* pt = partials + ((size_t)((b*Csz + c)*NCH + chunk))*NCOPY*33;
    reduce_store(s0, s1, s2, pt, lane);
}

// ---------------------------------------------------------------------------
// Fused finalize(prev) + E + M. Block=(b,chunk), 10 waves = 10 classes.
// No atomics / fences (round-7 fence finalize cost +180us on em2).
// ---------------------------------------------------------------------------
__global__ __launch_bounds__(BLK) void em_kernel(
    const float* __restrict__ pose,     // [B][N][16]
    const float* __restrict__ act,      // [B][N]
    const float* __restrict__ w,        // [I][C][16]
    const float* __restrict__ beta_v,   // [C]
    const float* __restrict__ beta_a,   // [C]
    const float* __restrict__ part_in,  // [B*C][NCH][8][33]
    float* __restrict__ part_out,       // [B*C][NCH][8][33]
    float inv_temp_prev)
{
    const int b = blockIdx.x, chunk = blockIdx.y;
    const int tid = threadIdx.x, wv = tid >> 6, lane = tid & 63;
    const int base = chunk * CH;

    __shared__ float Pl[4*CH*4];        // 28672 B
    __shared__ float zz[CH][11];        // 19712 B (stride 11 coprime 32)
    __shared__ float Sv[Csz][33];
    __shared__ float prm[Csz][33];      // mean16, invd16, K
    __shared__ float lg[Csz][16];

    const float* poseb = pose + (size_t)b * Nsz * Dsz;
    stage_pose(poseb, base, tid, Pl);

    float Wr[16];
    load_W_regs(w, lane, wv, Wr);

    // ---- phase F: reduce prev partials (14 chunks x 8 copies) -> prm ----
    if (tid < Csz*33) {
        int c = tid / 33, j = tid - c*33;
        const float* pp = part_in + ((size_t)(b*Csz + c)*NCH)*NCOPY*33 + j;
        float s = 0.f;
        for (int t = 0; t < NCH*NCOPY; ++t) s += pp[t*33];
        Sv[c][j] = s;
    }
    __syncthreads();
    if (tid < Csz*Dsz) {
        int c = tid >> 4, d = tid & 15;
        float S0 = Sv[c][0];
        float mn  = Sv[c][1+d] / S0;
        float var = fmaxf(Sv[c][17+d] / S0 - mn*mn, 0.f);
        prm[c][d]    = mn;
        prm[c][16+d] = 1.f / (2.f*var + EPSF);
        lg[c][d]     = __logf(sqrtf(var) + EPSF);
    }
    __syncthreads();
    if (tid < Csz) {
        int c = tid;
        float sumlog = 0.f;
#pragma unroll
        for (int d = 0; d < Dsz; ++d) sumlog += lg[c][d];
        float cost = Sv[c][0] * (16.f * beta_v[c] + sumlog);
        float oact = 1.f / (1.f + __expf(-inv_temp_prev * (beta_a[c] - cost)));
        prm[c][32] = __logf(oact + EPSF) - sumlog;    // K[c]
    }
    __syncthreads();

    // ---- E phase: wave wv computes zz[.][wv]; quad as 4-way tree ----
    {
        float mn[Dsz], iv[Dsz];
#pragma unroll
        for (int d = 0; d < Dsz; ++d) { mn[d] = prm[wv][d]; iv[d] = prm[wv][16+d]; }
        float Kc = prm[wv][32];

        for (int it = 0; it < ITER; ++it) {
            const int nl = it*64 + lane;
            const int n  = base + nl;
            float p[16];
            load_pose_lds(Pl, nl, p);
            int hw = n >> 5;
            int wc = hw % Ssz, hr = hw / Ssz;
            float v[16];
            vote_reg(p, Wr, (hr+0.5f)*(1.0f/Ssz), (wc+0.5f)*(1.0f/Ssz), v);
            float qa = 0.f, qb = 0.f, qc = 0.f, qd = 0.f;
#pragma unroll
            for (int d = 0; d < 4; ++d) {
                float d0 = v[d]    - mn[d];    qa += d0*d0*iv[d];
                float d1 = v[4+d]  - mn[4+d];  qb += d1*d1*iv[4+d];
                float d2 = v[8+d]  - mn[8+d];  qc += d2*d2*iv[8+d];
                float d3 = v[12+d] - mn[12+d]; qd += d3*d3*iv[12+d];
            }
            zz[nl][wv] = Kc - ((qa+qb)+(qc+qd));
        }
    }
    __syncthreads();

    // ---- softmax over c: thread-per-n (first CH threads), in place ----
    if (tid < CH) {
        const int n = base + tid;
        float z[Csz];
#pragma unroll
        for (int c = 0; c < Csz; ++c) z[c] = zz[tid][c];
        float zmax = z[0];
#pragma unroll
        for (int c = 1; c < Csz; ++c) zmax = fmaxf(zmax, z[c]);
        float zsum = 0.f;
#pragma unroll
        for (int c = 0; c < Csz; ++c) { z[c] = __expf(z[c] - zmax); zsum += z[c]; }
        float sc = __fdividef(act[(size_t)b*Nsz + n], zsum);
#pragma unroll
        for (int c = 0; c < Csz; ++c) zz[tid][c] = z[c] * sc;
    }
    __syncthreads();

    // ---- M phase: wave wv accumulates (pose + rr from LDS) ----
    float s0 = 0.f, s1[Dsz], s2[Dsz];
#pragma unroll
    for (int d = 0; d < Dsz; ++d) { s1[d] = 0.f; s2[d] = 0.f; }

    for (int it = 0; it < ITER; ++it) {
        const int nl = it*64 + lane;
        const int n  = base + nl;
        float p[16];
        load_pose_lds(Pl, nl, p);
        int hw = n >> 5;
        int wc = hw % Ssz, hr = hw / Ssz;
        float wgt = zz[nl][wv];
        float v[16];
        vote_reg(p, Wr, (hr+0.5f)*(1.0f/Ssz), (wc+0.5f)*(1.0f/Ssz), v);
        s0 += wgt;
#pragma unroll
        for (int d = 0; d < Dsz; ++d) {
            float wvv = wgt * v[d];
            s1[d] += wvv;
            s2[d] += wvv * v[d];
        }
    }

    float* pt = part_out + ((size_t)((b*Csz + wv)*NCH + chunk))*NCOPY*33;
    reduce_store(s0, s1, s2, pt, lane);
}

// ---------------------------------------------------------------------------
// Final finalize: one 64-thread block per (b,c). Threads j<33 sum the
// 14x8 partial copies in parallel; then 16 threads write mean; thread 0
// writes o_act (inv_temp=3).
// ---------------------------------------------------------------------------
__global__ __launch_bounds__(64) void fin_kernel(
    const float* __restrict__ partials, // [B*C][NCH][8][33]
    const float* __restrict__ beta_v,
    const float* __restrict__ beta_a,
    float* __restrict__ out,            // [B][C][16] then [B][C]
    float inv_temp)
{
    const int bc = blockIdx.x;
    const int c = bc % Csz;
    const int tid = threadIdx.x;

    __shared__ float S[33];
    __shared__ float lgs[16];

    if (tid < 33) {
        const float* pp = partials + (size_t)bc * NCH * NCOPY * 33 + tid;
        float s = 0.f;
        for (int t = 0; t < NCH*NCOPY; ++t) s += pp[t*33];
        S[tid] = s;
    }
    __syncthreads();
    if (tid < Dsz) {
        float S0 = S[0];
        float mn  = S[1+tid] / S0;
        float var = fmaxf(S[17+tid] / S0 - mn*mn, 0.f);
        lgs[tid] = __logf(sqrtf(var) + EPSF);
        out[(size_t)bc * Dsz + tid] = mn;
    }
    __syncthreads();
    if (tid == 0) {
        float sumlog = 0.f;
#pragma unroll
        for (int d = 0; d < Dsz; ++d) sumlog += lgs[d];
        float cost = S[0] * (16.f * beta_v[c] + sumlog);
        float oact = 1.f / (1.f + __expf(-inv_temp * (beta_a[c] - cost)));
        out[Bsz*Csz*Dsz + bc] = oact;
    }
}

// ---------------------------------------------------------------------------
// 4 dispatches: M0 -> EM1 -> EM2 -> FIN.
// Workspace: partials A,B = 2 x 640*14*8*33 floats = 9.46 MB.
// ---------------------------------------------------------------------------
extern "C" void kernel_launch(void* const* d_in, const int* in_sizes, int n_in,
                              void* d_out, int out_size, void* d_ws, size_t ws_size,
                              hipStream_t stream)
{
    const float* pose = (const float*)d_in[0];
    const float* act  = (const float*)d_in[1];
    const float* w    = (const float*)d_in[2];
    const float* bv   = (const float*)d_in[3];
    const float* ba   = (const float*)d_in[4];
    float* out = (float*)d_out;

    float* partA = (float*)d_ws;
    float* partB = partA + (size_t)Bsz*Csz*NCH*NCOPY*33;

    dim3 grid(Bsz, NCH);

    m0_kernel<<<grid, BLK, 0, stream>>>(pose, act, w, partA);
    em_kernel<<<grid, BLK, 0, stream>>>(pose, act, w, bv, ba, partA, partB, 1.0f);
    em_kernel<<<grid, BLK, 0, stream>>>(pose, act, w, bv, ba, partB, partA, 2.0f);
    fin_kernel<<<Bsz*Csz, 64, 0, stream>>>(partA, bv, ba, out, 3.0f);
}